// Round 1
// baseline (99.267 us; speedup 1.0000x reference)
//
#include <hip/hip_runtime.h>

#define B_  4
#define C_  64
#define H_  256
#define W_  256
#define h_  64
#define w_  64
// s = 4, off = 2, r = 2, inv_2ss2 = 1/(2*2.5^2) = 0.08
// log2-domain spatial weights: -(d^2)*0.08*log2(e)
#define L2SW2 (-0.46166241f)
#define L2SW1 (-0.11541560f)

// ---------------- per-batch partial sum / sumsq of guidance ------------------
// grid = 128 blocks (32 per batch); writes partials, NO atomics, no init needed.
__global__ void jbu_stats(const float* __restrict__ g, double* __restrict__ stats) {
    int b     = blockIdx.x >> 5;
    int slice = blockIdx.x & 31;
    // per batch: 3*256*256 = 196608 floats = 49152 float4; per block: 1536 float4
    const float4* p = (const float4*)(g + (size_t)b * 3 * H_ * W_) + (size_t)slice * 1536;
    double s = 0.0, s2 = 0.0;
    for (int i = threadIdx.x; i < 1536; i += 256) {
        float4 v = p[i];
        s  += (double)v.x + (double)v.y + (double)v.z + (double)v.w;
        s2 += (double)v.x * v.x + (double)v.y * v.y
            + (double)v.z * v.z + (double)v.w * v.w;
    }
    for (int off = 32; off > 0; off >>= 1) {
        s  += __shfl_down(s,  off);
        s2 += __shfl_down(s2, off);
    }
    __shared__ double ls[8];
    int wid  = threadIdx.x >> 6;
    int lane = threadIdx.x & 63;
    if (lane == 0) { ls[wid] = s; ls[4 + wid] = s2; }
    __syncthreads();
    if (threadIdx.x == 0) {
        stats[blockIdx.x]       = ls[0] + ls[1] + ls[2] + ls[3];
        stats[128 + blockIdx.x] = ls[4] + ls[5] + ls[6] + ls[7];
    }
}

// ---------------- fused main kernel ------------------------------------------
// 8 channels per block: grid = ((b*64 + y4)*8 + cg), 2048 blocks; block = 256.
// acc[4][8] = 32 VGPRs (was 64) -> ~5 waves/SIMD and ~2 block generations:
// round-2 staging overlaps round-1 compute/store drain (de-lockstep).
__global__ __launch_bounds__(256, 4)
void jbu_mega8(const float* __restrict__ src, const float* __restrict__ guid,
               const double* __restrict__ stats, float* __restrict__ out) {
    // src tile: 5 rows x 64 cols x 8 ch, stride padded to 12 floats (48 B):
    // 48 B keeps float4 alignment; read side: 16 addrs stride 48 B cover all 32
    // banks exactly twice (2-way = free); 4-lane broadcast per addr.
    __shared__ __align__(16) float sS[5 * 64 * 12];   // 15360 B
    // glow: (r,g,b, |gl|^2) per coarse pixel (raw ss; -invrl2 folded in tap fma
    // so sG staging does NOT depend on the stats reduction)
    __shared__ __align__(16) float sG[5 * 64 * 4];    //  5120 B

    int cg  = blockIdx.x & 7;
    int y4  = (blockIdx.x >> 3) & 63;
    int b   = blockIdx.x >> 9;
    int tid = threadIdx.x;

    int yi[5];
    #pragma unroll
    for (int d = 0; d < 5; ++d) {
        int u = y4 + d - 2;
        yi[d] = u < 0 ? 0 : (u > h_ - 1 ? h_ - 1 : u);
    }

    // ---- staging, split by wave pair so both streams issue immediately ------
    const float* sb = src + ((size_t)b * C_ + cg * 8) * h_ * w_;
    if (tid < 128) {
        // waves 0-1: source tile. 64 xx * 2 channel-quads; 5 rows each.
        int xx0 = tid & 63;
        int q4  = ((tid >> 6) & 1) * 4;    // channel-quad base (0 or 4)
        #pragma unroll
        for (int it = 0; it < 5; ++it) {
            int yy = yi[it];               // static index (unrolled)
            float4 v;
            v.x = sb[((size_t)(q4 + 0) * h_ + yy) * w_ + xx0];
            v.y = sb[((size_t)(q4 + 1) * h_ + yy) * w_ + xx0];
            v.z = sb[((size_t)(q4 + 2) * h_ + yy) * w_ + xx0];
            v.w = sb[((size_t)(q4 + 3) * h_ + yy) * w_ + xx0];
            *(float4*)&sS[(it * 64 + xx0) * 12 + q4] = v;
        }
    } else {
        // waves 2-3: low-res guidance + raw |gl|^2: 320 entries / 128 threads
        for (int k = tid - 128; k < 320; k += 128) {
            int xx  = k & 63;
            int row = k >> 6;
            int u   = y4 + row - 2;
            int yy  = u < 0 ? 0 : (u > h_ - 1 ? h_ - 1 : u);
            const float* gbase = guid + (size_t)b * 3 * H_ * W_
                               + (size_t)(yy * 4 + 2) * W_ + (xx * 4 + 2);
            float gx = gbase[0];
            float gy = gbase[H_ * W_];
            float gz = gbase[2 * H_ * W_];
            float ss = fmaf(gz, gz, fmaf(gy, gy, gx * gx));
            float4 e = make_float4(gx, gy, gz, ss);
            *(float4*)&sG[(row * 64 + xx) * 4] = e;
        }
    }

    // ---- inv_2sr2 (log2 domain) from partials; overlaps staging latency -----
    double S = 0.0, S2 = 0.0;
    for (int i = 0; i < 32; ++i) {
        S  += stats[b * 32 + i];
        S2 += stats[128 + b * 32 + i];
    }
    const double n = 3.0 * H_ * W_;
    double var = (S2 - S * S / n) / (n - 1.0);
    float invrl2 = (float)(2.0 / var) * 1.44269504f;   // includes log2(e)
    float ninv   = -invrl2;

    // ---- high-res guidance: premultiply by 2*invrl2; A_p = -invrl2*|gp|^2 ---
    int x  = tid;
    int y0 = y4 * 4;
    float gp[4][3];
    float A[4];
    #pragma unroll
    for (int c = 0; c < 3; ++c)
        #pragma unroll
        for (int p = 0; p < 4; ++p)
            gp[p][c] = guid[(((size_t)b * 3 + c) * H_ + (y0 + p)) * W_ + x];
    float t2 = 2.0f * invrl2;
    #pragma unroll
    for (int p = 0; p < 4; ++p) {
        float ss = fmaf(gp[p][2], gp[p][2], fmaf(gp[p][1], gp[p][1], gp[p][0] * gp[p][0]));
        A[p] = -invrl2 * ss;
        gp[p][0] *= t2; gp[p][1] *= t2; gp[p][2] *= t2;
    }

    __syncthreads();

    int xb = x >> 2;
    int xi[5];
    #pragma unroll
    for (int d = 0; d < 5; ++d) {
        int v = xb + d - 2;
        xi[d] = v < 0 ? 0 : (v > w_ - 1 ? w_ - 1 : v);
    }

    const float l2sw[5] = {L2SW2, L2SW1, 0.0f, L2SW1, L2SW2};

    float acc[4][8];
    float den[4];
    #pragma unroll
    for (int p = 0; p < 4; ++p) {
        den[p] = 0.0f;
        #pragma unroll
        for (int c = 0; c < 8; ++c) acc[p][c] = 0.0f;
    }

    #pragma unroll
    for (int dy = 0; dy < 5; ++dy) {
        float l2y = l2sw[dy];
        int   rb  = dy * 64;
        #pragma unroll
        for (int dx = 0; dx < 5; ++dx) {
            int xx = xi[dx];
            float4 gl = *(const float4*)&sG[(rb + xx) * 4];
            // ct = -invrl2*|gl|^2 + spatial(dy,dx); (l2y+l2sw[dx]) folds to const
            float ct = fmaf(gl.w, ninv, l2y + l2sw[dx]);
            float wgt[4];
            #pragma unroll
            for (int p = 0; p < 4; ++p) {
                float m = fmaf(gp[p][2], gl.z,
                          fmaf(gp[p][1], gl.y, gp[p][0] * gl.x));
                float wv = __builtin_amdgcn_exp2f(m + ct + A[p]);
                wgt[p] = wv;
                den[p] += wv;
            }
            const float* sP = &sS[(rb + xx) * 12];
            #pragma unroll
            for (int q = 0; q < 2; ++q) {
                float4 sv = *(const float4*)(sP + q * 4);
                #pragma unroll
                for (int p = 0; p < 4; ++p) {
                    acc[p][q * 4 + 0] = fmaf(wgt[p], sv.x, acc[p][q * 4 + 0]);
                    acc[p][q * 4 + 1] = fmaf(wgt[p], sv.y, acc[p][q * 4 + 1]);
                    acc[p][q * 4 + 2] = fmaf(wgt[p], sv.z, acc[p][q * 4 + 2]);
                    acc[p][q * 4 + 3] = fmaf(wgt[p], sv.w, acc[p][q * 4 + 3]);
                }
            }
        }
    }

    // ---- epilogue: 8 channels, nontemporal (write-once, keep L2 for reuse) --
    float* ob = out + ((size_t)b * C_ + cg * 8) * H_ * W_;
    #pragma unroll
    for (int p = 0; p < 4; ++p) {
        float r = 1.0f / (den[p] + 1e-8f);
        int row = (y0 + p) * W_ + x;
        #pragma unroll
        for (int c = 0; c < 8; ++c) {
            __builtin_nontemporal_store(acc[p][c] * r, &ob[(size_t)c * H_ * W_ + row]);
        }
    }
}

extern "C" void kernel_launch(void* const* d_in, const int* in_sizes, int n_in,
                              void* d_out, int out_size, void* d_ws, size_t ws_size,
                              hipStream_t stream) {
    const float* src  = (const float*)d_in[0];   // (4,64,64,64)
    const float* guid = (const float*)d_in[1];   // (4,3,256,256)
    float* out = (float*)d_out;                  // (4,64,256,256)

    double* stats = (double*)d_ws;               // 256 doubles: sum[128], sumsq[128]

    jbu_stats<<<128, 256, 0, stream>>>(guid, stats);
    jbu_mega8<<<B_ * 64 * 8, 256, 0, stream>>>(src, guid, stats, out);
}

// Round 3
// 98.126 us; speedup vs baseline: 1.0116x; 1.0116x over previous
//
#include <hip/hip_runtime.h>

#define B_  4
#define C_  64
#define H_  256
#define W_  256
#define h_  64
#define w_  64
// s = 4, off = 2, r = 2, inv_2ss2 = 1/(2*2.5^2) = 0.08
// log2-domain spatial weights: -(d^2)*0.08*log2(e)
#define L2SW2 (-0.46166241f)
#define L2SW1 (-0.11541560f)

typedef float v2f __attribute__((ext_vector_type(2)));

// ---------------- per-batch partial sum / sumsq of guidance ------------------
// grid = 32 blocks (8 per batch); writes partials, NO atomics, no init needed.
__global__ void jbu_stats(const float* __restrict__ g, double* __restrict__ stats) {
    int b     = blockIdx.x >> 3;
    int slice = blockIdx.x & 7;
    // per batch: 3*256*256 = 196608 floats = 49152 float4; per block: 6144 float4
    const float4* p = (const float4*)(g + (size_t)b * 3 * H_ * W_) + (size_t)slice * 6144;
    double s = 0.0, s2 = 0.0;
    for (int i = threadIdx.x; i < 6144; i += 256) {
        float4 v = p[i];
        s  += (double)v.x + (double)v.y + (double)v.z + (double)v.w;
        s2 += (double)v.x * v.x + (double)v.y * v.y
            + (double)v.z * v.z + (double)v.w * v.w;
    }
    for (int off = 32; off > 0; off >>= 1) {
        s  += __shfl_down(s,  off);
        s2 += __shfl_down(s2, off);
    }
    __shared__ double ls[8];
    int wid  = threadIdx.x >> 6;
    int lane = threadIdx.x & 63;
    if (lane == 0) { ls[wid] = s; ls[4 + wid] = s2; }
    __syncthreads();
    if (threadIdx.x == 0) {
        stats[blockIdx.x]      = ls[0] + ls[1] + ls[2] + ls[3];
        stats[32 + blockIdx.x] = ls[4] + ls[5] + ls[6] + ls[7];
    }
}

// ---------------- fused main kernel ------------------------------------------
// grid = ((b*64 + y4)*4 + cg), 1024 blocks; block = 256 (lane = fine x)
// thread: 4 fine y (y4*4+p) x fixed x x 16 channels (cg*16..)
__global__ __launch_bounds__(256, 4)
void jbu_mega16(const float* __restrict__ src, const float* __restrict__ guid,
                const double* __restrict__ stats, float* __restrict__ out) {
    // src tile: 5 rows x 64 cols x 16 ch, stride padded to 20 floats (80 B):
    // read side: 4 lanes broadcast same addr, 16 xb values -> ~2 addrs/bank = free.
    __shared__ __align__(16) float sS[5 * 64 * 20];   // 25600 B
    // glow: (r,g,b, |gl|^2) per coarse pixel (raw ss; -invrl2 folded per tap so
    // sG staging does NOT depend on the stats reduction)
    __shared__ __align__(16) float sG[5 * 64 * 4];    //  5120 B

    int cg  = blockIdx.x & 3;
    int y4  = (blockIdx.x >> 2) & 63;
    int b   = blockIdx.x >> 8;
    int tid = threadIdx.x;

    int yi[5];
    #pragma unroll
    for (int d = 0; d < 5; ++d) {
        int u = y4 + d - 2;
        yi[d] = u < 0 ? 0 : (u > h_ - 1 ? h_ - 1 : u);
    }

    // ---- stage source tile: per iter 4 coalesced dword loads + 1 b128 write
    //      (entries: 5 rows x 64 xx x 4 ch-quads; threads = 64 xx x 4 quads)
    const float* sb = src + ((size_t)b * C_ + cg * 16) * h_ * w_;
    {
        int xx0 = tid & 63;
        int j4  = ((tid >> 6) & 3) * 4;    // channel-quad base
        #pragma unroll
        for (int it = 0; it < 5; ++it) {
            int yy = yi[it];               // static index (unrolled)
            float4 v;
            v.x = sb[((size_t)(j4 + 0) * h_ + yy) * w_ + xx0];
            v.y = sb[((size_t)(j4 + 1) * h_ + yy) * w_ + xx0];
            v.z = sb[((size_t)(j4 + 2) * h_ + yy) * w_ + xx0];
            v.w = sb[((size_t)(j4 + 3) * h_ + yy) * w_ + xx0];
            *(float4*)&sS[(it * 64 + xx0) * 20 + j4] = v;
        }
    }
    // ---- stage low-res guidance + raw |gl|^2: 320 entries, 2 strided iters --
    for (int k = tid; k < 320; k += 256) {
        int xx  = k & 63;
        int row = k >> 6;
        int u   = y4 + row - 2;
        int yy  = u < 0 ? 0 : (u > h_ - 1 ? h_ - 1 : u);
        const float* gbase = guid + (size_t)b * 3 * H_ * W_
                           + (size_t)(yy * 4 + 2) * W_ + (xx * 4 + 2);
        float gx = gbase[0];
        float gy = gbase[H_ * W_];
        float gz = gbase[2 * H_ * W_];
        float ss = fmaf(gz, gz, fmaf(gy, gy, gx * gx));
        float4 e = make_float4(gx, gy, gz, ss);
        *(float4*)&sG[(row * 64 + xx) * 4] = e;
    }

    // ---- inv_2sr2 (log2 domain) from partials; overlaps staging latency -----
    double S = 0.0, S2 = 0.0;
    for (int i = 0; i < 8; ++i) {
        S  += stats[b * 8 + i];
        S2 += stats[32 + b * 8 + i];
    }
    const double n = 3.0 * H_ * W_;
    double var = (S2 - S * S / n) / (n - 1.0);
    float invrl2 = (float)(2.0 / var) * 1.44269504f;   // includes log2(e)
    float ninv   = -invrl2;

    // ---- high-res guidance (independent of LDS; overlaps barrier) -----------
    int x  = tid;
    int y0 = y4 * 4;
    float gp[4][3];
    float A[4];
    #pragma unroll
    for (int c = 0; c < 3; ++c)
        #pragma unroll
        for (int p = 0; p < 4; ++p)
            gp[p][c] = guid[(((size_t)b * 3 + c) * H_ + (y0 + p)) * W_ + x];
    float t2 = 2.0f * invrl2;
    #pragma unroll
    for (int p = 0; p < 4; ++p) {
        float ss = fmaf(gp[p][2], gp[p][2], fmaf(gp[p][1], gp[p][1], gp[p][0] * gp[p][0]));
        A[p] = -invrl2 * ss;
        gp[p][0] *= t2; gp[p][1] *= t2; gp[p][2] *= t2;
    }

    __syncthreads();

    int xb = x >> 2;
    int xi[5];
    #pragma unroll
    for (int d = 0; d < 5; ++d) {
        int v = xb + d - 2;
        xi[d] = v < 0 ? 0 : (v > w_ - 1 ? w_ - 1 : v);
    }

    const float l2sw[5] = {L2SW2, L2SW1, 0.0f, L2SW1, L2SW2};

    // acc as float2 pairs: v_pk_fma_f32 (packed f32) ~halves the dominant VALU.
    v2f accv[4][8];
    float den[4];
    #pragma unroll
    for (int p = 0; p < 4; ++p) {
        den[p] = 0.0f;
        #pragma unroll
        for (int j = 0; j < 8; ++j) { accv[p][j].x = 0.0f; accv[p][j].y = 0.0f; }
    }

    #pragma unroll
    for (int dy = 0; dy < 5; ++dy) {
        float l2y = l2sw[dy];
        int   rb  = dy * 64;
        #pragma unroll
        for (int dx = 0; dx < 5; ++dx) {
            int xx = xi[dx];
            float4 gl = *(const float4*)&sG[(rb + xx) * 4];
            // ct = -invrl2*|gl|^2 + spatial(dy,dx); (l2y+l2sw[dx]) folds to const
            float ct = fmaf(gl.w, ninv, l2y + l2sw[dx]);
            v2f w2[4];
            #pragma unroll
            for (int p = 0; p < 4; ++p) {
                float m = fmaf(gp[p][2], gl.z,
                          fmaf(gp[p][1], gl.y,
                          fmaf(gp[p][0], gl.x, ct + A[p])));
                float wv = __builtin_amdgcn_exp2f(m);
                w2[p].x = wv; w2[p].y = wv;      // aligned pair for v_pk_fma_f32
                den[p] += wv;
            }
            const float* sP = &sS[(rb + xx) * 20];
            #pragma unroll
            for (int q = 0; q < 4; ++q) {
                v2f lo = *(const v2f*)(sP + q * 4);
                v2f hi = *(const v2f*)(sP + q * 4 + 2);
                #pragma unroll
                for (int p = 0; p < 4; ++p) {
                    // all operands are 64-bit aligned VGPR pairs (VOP3P-legal)
                    asm("v_pk_fma_f32 %0, %1, %2, %0"
                        : "+v"(accv[p][q * 2 + 0]) : "v"(w2[p]), "v"(lo));
                    asm("v_pk_fma_f32 %0, %1, %2, %0"
                        : "+v"(accv[p][q * 2 + 1]) : "v"(w2[p]), "v"(hi));
                }
            }
        }
    }

    // ---- epilogue: nontemporal (write-once; keep L2 for guidance/src reuse) -
    float* ob = out + ((size_t)b * C_ + cg * 16) * H_ * W_;
    #pragma unroll
    for (int p = 0; p < 4; ++p) {
        float r = 1.0f / (den[p] + 1e-8f);
        int row = (y0 + p) * W_ + x;
        #pragma unroll
        for (int j = 0; j < 8; ++j) {
            __builtin_nontemporal_store(accv[p][j].x * r, &ob[(size_t)(2 * j + 0) * H_ * W_ + row]);
            __builtin_nontemporal_store(accv[p][j].y * r, &ob[(size_t)(2 * j + 1) * H_ * W_ + row]);
        }
    }
}

extern "C" void kernel_launch(void* const* d_in, const int* in_sizes, int n_in,
                              void* d_out, int out_size, void* d_ws, size_t ws_size,
                              hipStream_t stream) {
    const float* src  = (const float*)d_in[0];   // (4,64,64,64)
    const float* guid = (const float*)d_in[1];   // (4,3,256,256)
    float* out = (float*)d_out;                  // (4,64,256,256)

    double* stats = (double*)d_ws;               // 64 doubles: sum[32], sumsq[32]

    jbu_stats<<<32, 256, 0, stream>>>(guid, stats);
    jbu_mega16<<<B_ * 64 * 4, 256, 0, stream>>>(src, guid, stats, out);
}